// Round 6
// baseline (263.621 us; speedup 1.0000x reference)
//
#include <hip/hip_runtime.h>
#include <math.h>

typedef short bf8v __attribute__((ext_vector_type(8)));   // 8 bf16 (4 VGPR) MFMA frag
typedef float f32x4 __attribute__((ext_vector_type(4)));  // MFMA acc

#define SCALE 0.17677669529663687f  // 1/sqrt(32)

__device__ __forceinline__ unsigned short f2bf(float f) {
    union { float f; unsigned int u; } c; c.f = f;
    unsigned int r = (c.u + 0x7FFFu + ((c.u >> 16) & 1u)) >> 16;  // RNE
    return (unsigned short)r;
}

// LDS index helpers (element index into ushort arrays).
// [rows][32] bf16 tile, 16B slots; slot XOR (row>>1)&3 -> frag reads are 2-way (free)
__device__ __forceinline__ int sw32(int row, int k8) {
    return row * 32 + ((k8 ^ ((row >> 1) & 3)) << 3);
}
// [rows][128] bf16 tile, 16 slots; slot XOR row&15 -> frag reads perfect 2-way
__device__ __forceinline__ int sw128(int row, int c8) {
    return row * 128 + (((c8 ^ row) & 15) << 3);
}
// bounce buffer [128][128] bf16: XOR chunk bits 1..2 with row-quad -> conflict-free
__device__ __forceinline__ int bidx(int row, int col) {
    return row * 128 + ((((col >> 3) ^ (((row >> 2) & 3) << 1)) & 15) << 3) + (col & 7);
}

// ---------- pre-kernel: both weights [256][C] fp32 -> [C][256] bf16 ----------
__global__ __launch_bounds__(256) void tcvt_w_kernel(const float* __restrict__ w1,
                                                     const float* __restrict__ w2,
                                                     unsigned short* __restrict__ wtq,
                                                     unsigned short* __restrict__ wtp) {
    int idx = blockIdx.x * 256 + threadIdx.x;
    if (idx < 768 * 256) {
        int c = idx >> 8, r = idx & 255;
        wtq[idx] = f2bf(w1[r * 768 + c]);
    } else {
        int i2 = idx - 768 * 256;
        int c = i2 >> 8, r = i2 & 255;
        wtp[i2] = f2bf(w2[r * 256 + c]);
    }
}

// ---------- pre-kernel: bm[w][h] = [112][112] fp32; pads baked in ----------
// col>=98 -> -1e30 (softmax zero); row 98..111 (col<98) -> 0 (harmless pad rows)
__global__ __launch_bounds__(256) void bm_kernel(const float* __restrict__ bias_table,
                                                 const int* __restrict__ rpi,
                                                 const float* __restrict__ mask,
                                                 float* __restrict__ bm) {
    int bx = blockIdx.x;               // bx = w*8 + h
    int w = bx >> 3, h = bx & 7;
    const float* mp = mask + (size_t)w * 9604;
    float* op = bm + (size_t)bx * 12544;
    int t = threadIdx.x;
    if (t >= 224) return;
    int r0 = (t >= 112) ? 1 : 0;
    int col = t - 112 * r0;
    for (int row = r0; row < 112; row += 2) {
        float val;
        if (col >= 98)      val = -1e30f;
        else if (row >= 98) val = 0.0f;
        else                val = bias_table[rpi[row * 98 + col] * 8 + h] + mp[row * 98 + col];
        op[row * 112 + col] = val;
    }
}

// ---------- Kernel 1: qkv GEMM (fused fp32->bf16 of x) -> packed qkv [M][768], q pre-scaled ----------
// M=50176, K=256, N=768. 128x128 tile, BK=32, 4 waves. Grid 2352 = 8 XCD * 294 (cols fastest).
__global__ __launch_bounds__(256) void qkv_gemm_kernel(
    const float* __restrict__ x, const unsigned short* __restrict__ B,
    const float* __restrict__ bias, unsigned short* __restrict__ qkv)
{
    __shared__ unsigned short As[128 * 32];
    __shared__ unsigned short Bs[128 * 32];
    __shared__ unsigned short Cb[128 * 128];
    const int tid = threadIdx.x;
    const int lane = tid & 63, wid = tid >> 6;
    const int l16 = lane & 15, lg = lane >> 4;
    const int wr = wid >> 1, wc = wid & 1;
    const int nb = (blockIdx.x & 7) * 294 + (blockIdx.x >> 3);
    const int bm0 = (nb / 6) * 128, bn0 = (nb % 6) * 128;

    f32x4 acc[4][4] = {};
    const int crow = tid >> 2, ck8 = tid & 3;  // staging chunk (16B of bf16 / 32B of fp32)

    for (int k0 = 0; k0 < 256; k0 += 32) {
        __syncthreads();
        #pragma unroll
        for (int rr = 0; rr < 2; ++rr) {
            const float* xp = x + (size_t)(bm0 + crow + rr * 64) * 256 + k0 + ck8 * 8;
            const float4 a0 = *(const float4*)xp;
            const float4 a1 = *(const float4*)(xp + 4);
            union { int4 v; unsigned short u[8]; } o;
            o.u[0]=f2bf(a0.x); o.u[1]=f2bf(a0.y); o.u[2]=f2bf(a0.z); o.u[3]=f2bf(a0.w);
            o.u[4]=f2bf(a1.x); o.u[5]=f2bf(a1.y); o.u[6]=f2bf(a1.z); o.u[7]=f2bf(a1.w);
            *(int4*)&As[sw32(crow + rr * 64, ck8)] = o.v;
        }
        *(int4*)&Bs[sw32(crow,      ck8)] = *(const int4*)(B + (size_t)(bn0 + crow     ) * 256 + k0 + ck8 * 8);
        *(int4*)&Bs[sw32(crow + 64, ck8)] = *(const int4*)(B + (size_t)(bn0 + crow + 64) * 256 + k0 + ck8 * 8);
        __syncthreads();
        bf8v af[4], bfr[4];
        #pragma unroll
        for (int mt = 0; mt < 4; ++mt) af[mt]  = *(const bf8v*)&As[sw32(wr*64 + mt*16 + l16, lg)];
        #pragma unroll
        for (int nt = 0; nt < 4; ++nt) bfr[nt] = *(const bf8v*)&Bs[sw32(wc*64 + nt*16 + l16, lg)];
        #pragma unroll
        for (int mt = 0; mt < 4; ++mt)
            #pragma unroll
            for (int nt = 0; nt < 4; ++nt)
                acc[mt][nt] = __builtin_amdgcn_mfma_f32_16x16x32_bf16(af[mt], bfr[nt], acc[mt][nt], 0, 0, 0);
    }

    // epilogue: bias+scale -> bf16 -> swizzled LDS bounce -> coalesced int4 stores
    #pragma unroll
    for (int nt = 0; nt < 4; ++nt) {
        const int colg = bn0 + wc * 64 + nt * 16 + l16;
        const float bv = bias[colg];
        const float sc = (colg < 256) ? SCALE : 1.0f;
        #pragma unroll
        for (int mt = 0; mt < 4; ++mt)
            #pragma unroll
            for (int r = 0; r < 4; ++r) {
                const int rl = wr * 64 + mt * 16 + lg * 4 + r;
                Cb[bidx(rl, wc * 64 + nt * 16 + l16)] = f2bf((acc[mt][nt][r] + bv) * sc);
            }
    }
    __syncthreads();
    #pragma unroll
    for (int c0 = 0; c0 < 8; ++c0) {
        const int c = c0 * 256 + tid;
        const int row = c >> 4, c8 = c & 15;
        const int4 val = *(const int4*)&Cb[row * 128 + (((c8 ^ (((row >> 2) & 3) << 1)) & 15) << 3)];
        *(int4*)(qkv + (size_t)(bm0 + row) * 768 + bn0 + c8 * 8) = val;
    }
}

// ---------- Kernel 2: per-(b,h) attention; LDS overlay (Ps over Qs+Ks) -> 36.9 KB, 4 blocks/CU ----------
__global__ __launch_bounds__(448) void attn_kernel(
    const unsigned short* __restrict__ qkv, const float* __restrict__ bm,
    unsigned short* __restrict__ att)
{
    __shared__ unsigned short SH[18432];       // 36,864 B
    unsigned short* Qs = SH;                   // 112*32  (dead after S-phase)
    unsigned short* Ks = SH + 3584;            // 112*32  (dead after S-phase)
    unsigned short* Ps = SH;                   // 112*128 (overlays Qs,Ks + 7168 more)
    unsigned short* Vt = SH + 14336;           // 32*128

    // swizzle: same-(w,h) b-repeats consecutive on one XCD -> bm panel L2-resident
    const int xcd = blockIdx.x & 7, i = blockIdx.x >> 3;
    const int j = i & 7, h = (i >> 3) & 7, wlo = i >> 6;
    const int w = xcd * 8 + wlo;
    const int b = (j << 6) + w;                // b & 63 == w
    const int tid = threadIdx.x;
    const int wid = tid >> 6, lane = tid & 63;
    const int l16 = lane & 15, lg = lane >> 4;
    const unsigned short* base = qkv + (size_t)b * 98 * 768 + h * 32;  // q; +256 k; +512 v

    // ---- stage Q,K (swizzled), V transposed; zero pads ----
    if (tid < 392) {
        const int row = tid >> 2, k8 = tid & 3;
        const unsigned short* rp = base + (size_t)row * 768 + k8 * 8;
        *(int4*)&Qs[sw32(row, k8)] = *(const int4*)(rp);
        *(int4*)&Ks[sw32(row, k8)] = *(const int4*)(rp + 256);
        union { int4 v; unsigned short u[8]; } t;
        t.v = *(const int4*)(rp + 512);   // V[row][8d]
        #pragma unroll
        for (int jj = 0; jj < 8; ++jj) {
            const int d = k8 * 8 + jj;
            Vt[sw128(d, row >> 3) + (row & 7)] = t.u[jj];
        }
    } else {
        const int t2 = tid - 392;                        // 56 threads: zero Q/K pad rows 98..111
        const int row = 98 + (t2 >> 2), k8 = t2 & 3;
        const int4 z = {0, 0, 0, 0};
        *(int4*)&Qs[sw32(row, k8)] = z;
        *(int4*)&Ks[sw32(row, k8)] = z;
    }
    for (int e = tid; e < 32 * 30; e += 448) {           // zero Vt cols 98..127
        const int d = e / 30, n = 98 + e - (e / 30) * 30;
        Vt[sw128(d, n >> 3) + (n & 7)] = 0;
    }
    __syncthreads();

    // ---- S = Q@K^T for row-tile rt = wid ----
    const int rt = wid;
    const bf8v qf = *(const bf8v*)&Qs[sw32(rt * 16 + l16, lg)];
    f32x4 sa[7];
    const f32x4 zero = {0.f, 0.f, 0.f, 0.f};
    #pragma unroll
    for (int ct = 0; ct < 7; ++ct) {
        const bf8v kf = *(const bf8v*)&Ks[sw32(ct * 16 + l16, lg)];
        sa[ct] = __builtin_amdgcn_mfma_f32_16x16x32_bf16(qf, kf, zero, 0, 0, 0);
    }

    // ---- + bm[112][112] (pads baked in: col>=98 = -1e30, pad rows = 0) ----
    const float* bmp = bm + (size_t)(w * 8 + h) * 12544;
    #pragma unroll
    for (int ct = 0; ct < 7; ++ct) {
        const int col = ct * 16 + l16;
        #pragma unroll
        for (int r = 0; r < 4; ++r) {
            const int row = rt * 16 + lg * 4 + r;
            sa[ct][r] += bmp[row * 112 + col];
        }
    }

    // Q/K frags consumed -> safe to overwrite their LDS with Ps after this barrier
    __syncthreads();

    // ---- softmax per row (rows live in 16-lane groups), write P bf16 to Ps ----
    #pragma unroll
    for (int r = 0; r < 4; ++r) {
        float mx = sa[0][r];
        #pragma unroll
        for (int ct = 1; ct < 7; ++ct) mx = fmaxf(mx, sa[ct][r]);
        #pragma unroll
        for (int off = 1; off < 16; off <<= 1) mx = fmaxf(mx, __shfl_xor(mx, off));
        float sum = 0.f;
        #pragma unroll
        for (int ct = 0; ct < 7; ++ct) { const float e = __expf(sa[ct][r] - mx); sa[ct][r] = e; sum += e; }
        #pragma unroll
        for (int off = 1; off < 16; off <<= 1) sum += __shfl_xor(sum, off);
        const float inv = 1.0f / sum;
        const int row = rt * 16 + lg * 4 + r;
        #pragma unroll
        for (int ct = 0; ct < 7; ++ct) {
            const int col = ct * 16 + l16;
            Ps[sw128(row, col >> 3) + (col & 7)] = f2bf(sa[ct][r] * inv);
        }
    }
    // zero P pad cols 112..127 for this wave's rows (PV K-dim padding)
    #pragma unroll
    for (int e0 = 0; e0 < 4; ++e0) {
        const int e = e0 * 64 + lane;
        const int row = rt * 16 + (e >> 4), col = 112 + (e & 15);
        Ps[sw128(row, col >> 3) + (col & 7)] = 0;
    }
    // P is wave-local (each wave reads only its own rows) -> no barrier needed.

    // ---- O = P @ V ----
    f32x4 oacc[2] = {};
    #pragma unroll
    for (int ks = 0; ks < 4; ++ks) {
        const bf8v pf = *(const bf8v*)&Ps[sw128(rt * 16 + l16, ks * 4 + lg)];
        #pragma unroll
        for (int dt = 0; dt < 2; ++dt) {
            const bf8v vf = *(const bf8v*)&Vt[sw128(dt * 16 + l16, ks * 4 + lg)];
            oacc[dt] = __builtin_amdgcn_mfma_f32_16x16x32_bf16(pf, vf, oacc[dt], 0, 0, 0);
        }
    }

    // ---- store att[b][row][h*32 + d] bf16 ----
    #pragma unroll
    for (int r = 0; r < 4; ++r) {
        const int row = rt * 16 + lg * 4 + r;
        if (row < 98) {
            #pragma unroll
            for (int dt = 0; dt < 2; ++dt)
                att[((size_t)b * 98 + row) * 256 + h * 32 + dt * 16 + l16] = f2bf(oacc[dt][r]);
        }
    }
}

// ---------- Kernel 3: out = att @ proj_w + proj_b (bf16 MFMA, fp32 out) ----------
__global__ __launch_bounds__(256) void proj_gemm_kernel(
    const unsigned short* __restrict__ A, const unsigned short* __restrict__ B,
    const float* __restrict__ pb, float* __restrict__ out)
{
    __shared__ unsigned short As[128 * 32];
    __shared__ unsigned short Bs[128 * 32];
    const int tid = threadIdx.x;
    const int lane = tid & 63, wid = tid >> 6;
    const int l16 = lane & 15, lg = lane >> 4;
    const int wr = wid >> 1, wc = wid & 1;
    const int nb = (blockIdx.x & 7) * 98 + (blockIdx.x >> 3);
    const int bm0 = (nb >> 1) * 128, bn0 = (nb & 1) * 128;

    f32x4 acc[4][4] = {};
    const int crow = tid >> 2, ck8 = tid & 3;

    for (int k0 = 0; k0 < 256; k0 += 32) {
        __syncthreads();
        *(int4*)&As[sw32(crow,      ck8)] = *(const int4*)(A + (size_t)(bm0 + crow     ) * 256 + k0 + ck8 * 8);
        *(int4*)&As[sw32(crow + 64, ck8)] = *(const int4*)(A + (size_t)(bm0 + crow + 64) * 256 + k0 + ck8 * 8);
        *(int4*)&Bs[sw32(crow,      ck8)] = *(const int4*)(B + (size_t)(bn0 + crow     ) * 256 + k0 + ck8 * 8);
        *(int4*)&Bs[sw32(crow + 64, ck8)] = *(const int4*)(B + (size_t)(bn0 + crow + 64) * 256 + k0 + ck8 * 8);
        __syncthreads();
        bf8v af[4], bfr[4];
        #pragma unroll
        for (int mt = 0; mt < 4; ++mt) af[mt]  = *(const bf8v*)&As[sw32(wr*64 + mt*16 + l16, lg)];
        #pragma unroll
        for (int nt = 0; nt < 4; ++nt) bfr[nt] = *(const bf8v*)&Bs[sw32(wc*64 + nt*16 + l16, lg)];
        #pragma unroll
        for (int mt = 0; mt < 4; ++mt)
            #pragma unroll
            for (int nt = 0; nt < 4; ++nt)
                acc[mt][nt] = __builtin_amdgcn_mfma_f32_16x16x32_bf16(af[mt], bfr[nt], acc[mt][nt], 0, 0, 0);
    }

    #pragma unroll
    for (int mt = 0; mt < 4; ++mt)
        #pragma unroll
        for (int r = 0; r < 4; ++r) {
            const int row = bm0 + wr*64 + mt*16 + lg*4 + r;
            #pragma unroll
            for (int nt = 0; nt < 4; ++nt) {
                const int col = bn0 + wc*64 + nt*16 + l16;
                out[(size_t)row * 256 + col] = acc[mt][nt][r] + pb[col];
            }
        }
}

extern "C" void kernel_launch(void* const* d_in, const int* in_sizes, int n_in,
                              void* d_out, int out_size, void* d_ws, size_t ws_size,
                              hipStream_t stream) {
    const float* x          = (const float*)d_in[0];
    const float* qkv_w      = (const float*)d_in[1];
    const float* qkv_b      = (const float*)d_in[2];
    const float* bias_table = (const float*)d_in[3];
    const float* proj_w     = (const float*)d_in[4];
    const float* proj_b     = (const float*)d_in[5];
    const float* mask       = (const float*)d_in[6];
    const int*   rpi        = (const int*)d_in[7];
    float* out = (float*)d_out;

    // ws layout (ushorts unless noted): wtq | wtp | qkv | att | bm(f32)
    const size_t SEG = (size_t)50176 * 256;  // 12,845,056
    unsigned short* wtq  = (unsigned short*)d_ws;   // 768*256
    unsigned short* wtp  = wtq + 768 * 256;         // 256*256
    unsigned short* qkvb = wtp + 256 * 256;         // 3*SEG, packed [M][768]
    unsigned short* attb = qkvb + 3 * SEG;          // SEG
    float* bm = (float*)(attb + SEG);               // 512*12544 floats

    tcvt_w_kernel<<<1024, 256, 0, stream>>>(qkv_w, proj_w, wtq, wtp);
    bm_kernel<<<512, 256, 0, stream>>>(bias_table, rpi, mask, bm);

    qkv_gemm_kernel<<<2352, 256, 0, stream>>>(x, wtq, qkv_b, qkvb);
    attn_kernel<<<4096, 448, 0, stream>>>(qkvb, bm, attb);
    proj_gemm_kernel<<<784, 256, 0, stream>>>(attb, wtp, proj_b, out);
}

// Round 11
// 261.255 us; speedup vs baseline: 1.0091x; 1.0091x over previous
//
#include <hip/hip_runtime.h>
#include <hip/hip_bf16.h>
#include <math.h>

typedef short bf8v __attribute__((ext_vector_type(8)));   // 8 bf16 (4 VGPR) MFMA frag
typedef float f32x4 __attribute__((ext_vector_type(4)));  // MFMA acc

#define SCALE 0.17677669529663687f  // 1/sqrt(32)

// HW bf16 converts (RNE) — compiler lowers to v_cvt_pk_bf16_f32 / single cvt
__device__ __forceinline__ unsigned short f2bf(float f) {
    union { __hip_bfloat16 b; unsigned short u; } c;
    c.b = __float2bfloat16(f);
    return c.u;
}
__device__ __forceinline__ unsigned int f2bf2(float lo, float hi) {
    union { __hip_bfloat162 b2; unsigned int u; } c;
    c.b2 = __float22bfloat162_rn(float2{lo, hi});
    return c.u;
}

// LDS index helpers (element index into ushort arrays).
// [rows][32] bf16 tile, 16B slots; slot XOR (row>>1)&3 -> frag reads are 2-way (free)
__device__ __forceinline__ int sw32(int row, int k8) {
    return row * 32 + ((k8 ^ ((row >> 1) & 3)) << 3);
}
// [rows][128] bf16 tile, 16 slots; slot XOR row&15 -> frag reads perfect 2-way
__device__ __forceinline__ int sw128(int row, int c8) {
    return row * 128 + (((c8 ^ row) & 15) << 3);
}
// bounce buffer [128][128] bf16: XOR chunk bits 1..2 with row-quad -> conflict-free
__device__ __forceinline__ int bidx(int row, int col) {
    return row * 128 + ((((col >> 3) ^ (((row >> 2) & 3) << 1)) & 15) << 3) + (col & 7);
}

// ---------- pre-kernel: both weights [256][C] fp32 -> [C][256] bf16 ----------
__global__ __launch_bounds__(256) void tcvt_w_kernel(const float* __restrict__ w1,
                                                     const float* __restrict__ w2,
                                                     unsigned short* __restrict__ wtq,
                                                     unsigned short* __restrict__ wtp) {
    int idx = blockIdx.x * 256 + threadIdx.x;
    if (idx < 768 * 256) {
        int c = idx >> 8, r = idx & 255;
        wtq[idx] = f2bf(w1[r * 768 + c]);
    } else {
        int i2 = idx - 768 * 256;
        int c = i2 >> 8, r = i2 & 255;
        wtp[i2] = f2bf(w2[r * 256 + c]);
    }
}

// ---------- pre-kernel: bm[w][h] = [112][112] fp32; pads baked in ----------
// col>=98 -> -1e30 (softmax zero); row 98..111 (col<98) -> 0 (harmless pad rows)
__global__ __launch_bounds__(256) void bm_kernel(const float* __restrict__ bias_table,
                                                 const int* __restrict__ rpi,
                                                 const float* __restrict__ mask,
                                                 float* __restrict__ bm) {
    int bx = blockIdx.x;               // bx = w*8 + h
    int w = bx >> 3, h = bx & 7;
    const float* mp = mask + (size_t)w * 9604;
    float* op = bm + (size_t)bx * 12544;
    int t = threadIdx.x;
    if (t >= 224) return;
    int r0 = (t >= 112) ? 1 : 0;
    int col = t - 112 * r0;
    for (int row = r0; row < 112; row += 2) {
        float val;
        if (col >= 98)      val = -1e30f;
        else if (row >= 98) val = 0.0f;
        else                val = bias_table[rpi[row * 98 + col] * 8 + h] + mp[row * 98 + col];
        op[row * 112 + col] = val;
    }
}

// ---------- Kernel 1: qkv GEMM (fused fp32->bf16 of x) -> packed qkv [M][768], q pre-scaled ----------
// M=50176, K=256, N=768. 128x128 tile, BK=32, 4 waves. Grid 2352 = 8 XCD * 294 (cols fastest).
// LDS: one 32 KB pool; Cb (epilogue) aliases As+Bs (dead after last frag read).
__global__ __launch_bounds__(256) void qkv_gemm_kernel(
    const float* __restrict__ x, const unsigned short* __restrict__ B,
    const float* __restrict__ bias, unsigned short* __restrict__ qkv)
{
    __shared__ unsigned short SH[16384];   // 32 KB
    unsigned short* As = SH;               // 128*32
    unsigned short* Bs = SH + 4096;        // 128*32
    unsigned short* Cb = SH;               // 128*128, epilogue alias

    const int tid = threadIdx.x;
    const int lane = tid & 63, wid = tid >> 6;
    const int l16 = lane & 15, lg = lane >> 4;
    const int wr = wid >> 1, wc = wid & 1;
    const int nb = (blockIdx.x & 7) * 294 + (blockIdx.x >> 3);
    const int bm0 = (nb / 6) * 128, bn0 = (nb % 6) * 128;

    f32x4 acc[4][4] = {};
    const int crow = tid >> 2, ck8 = tid & 3;  // staging chunk (16B of bf16 / 32B of fp32)

    for (int k0 = 0; k0 < 256; k0 += 32) {
        __syncthreads();
        #pragma unroll
        for (int rr = 0; rr < 2; ++rr) {
            const float* xp = x + (size_t)(bm0 + crow + rr * 64) * 256 + k0 + ck8 * 8;
            const float4 a0 = *(const float4*)xp;
            const float4 a1 = *(const float4*)(xp + 4);
            union { int4 v; unsigned int w[4]; } o;
            o.w[0] = f2bf2(a0.x, a0.y);
            o.w[1] = f2bf2(a0.z, a0.w);
            o.w[2] = f2bf2(a1.x, a1.y);
            o.w[3] = f2bf2(a1.z, a1.w);
            *(int4*)&As[sw32(crow + rr * 64, ck8)] = o.v;
        }
        *(int4*)&Bs[sw32(crow,      ck8)] = *(const int4*)(B + (size_t)(bn0 + crow     ) * 256 + k0 + ck8 * 8);
        *(int4*)&Bs[sw32(crow + 64, ck8)] = *(const int4*)(B + (size_t)(bn0 + crow + 64) * 256 + k0 + ck8 * 8);
        __syncthreads();
        bf8v af[4], bfr[4];
        #pragma unroll
        for (int mt = 0; mt < 4; ++mt) af[mt]  = *(const bf8v*)&As[sw32(wr*64 + mt*16 + l16, lg)];
        #pragma unroll
        for (int nt = 0; nt < 4; ++nt) bfr[nt] = *(const bf8v*)&Bs[sw32(wc*64 + nt*16 + l16, lg)];
        #pragma unroll
        for (int mt = 0; mt < 4; ++mt)
            #pragma unroll
            for (int nt = 0; nt < 4; ++nt)
                acc[mt][nt] = __builtin_amdgcn_mfma_f32_16x16x32_bf16(af[mt], bfr[nt], acc[mt][nt], 0, 0, 0);
    }

    __syncthreads();   // all As/Bs frag reads done before Cb alias overwrite

    // epilogue: bias+scale -> bf16 -> swizzled LDS bounce -> coalesced int4 stores
    #pragma unroll
    for (int nt = 0; nt < 4; ++nt) {
        const int colg = bn0 + wc * 64 + nt * 16 + l16;
        const float bv = bias[colg];
        const float sc = (colg < 256) ? SCALE : 1.0f;
        #pragma unroll
        for (int mt = 0; mt < 4; ++mt)
            #pragma unroll
            for (int r = 0; r < 4; ++r) {
                const int rl = wr * 64 + mt * 16 + lg * 4 + r;
                Cb[bidx(rl, wc * 64 + nt * 16 + l16)] = f2bf((acc[mt][nt][r] + bv) * sc);
            }
    }
    __syncthreads();
    #pragma unroll
    for (int c0 = 0; c0 < 8; ++c0) {
        const int c = c0 * 256 + tid;
        const int row = c >> 4, c8 = c & 15;
        const int4 val = *(const int4*)&Cb[row * 128 + (((c8 ^ (((row >> 2) & 3) << 1)) & 15) << 3)];
        *(int4*)(qkv + (size_t)(bm0 + row) * 768 + bn0 + c8 * 8) = val;
    }
}

// ---------- Kernel 2: per-(b,h) attention; LDS overlay (Ps over Qs+Ks) -> 36.9 KB, 4 blocks/CU ----------
__global__ __launch_bounds__(448) void attn_kernel(
    const unsigned short* __restrict__ qkv, const float* __restrict__ bm,
    unsigned short* __restrict__ att)
{
    __shared__ unsigned short SH[18432];       // 36,864 B
    unsigned short* Qs = SH;                   // 112*32  (dead after S-phase)
    unsigned short* Ks = SH + 3584;            // 112*32  (dead after S-phase)
    unsigned short* Ps = SH;                   // 112*128 (overlays Qs,Ks + 7168 more)
    unsigned short* Vt = SH + 14336;           // 32*128

    // swizzle: same-(w,h) b-repeats consecutive on one XCD -> bm panel L2-resident
    const int xcd = blockIdx.x & 7, i = blockIdx.x >> 3;
    const int j = i & 7, h = (i >> 3) & 7, wlo = i >> 6;
    const int w = xcd * 8 + wlo;
    const int b = (j << 6) + w;                // b & 63 == w
    const int tid = threadIdx.x;
    const int wid = tid >> 6, lane = tid & 63;
    const int l16 = lane & 15, lg = lane >> 4;
    const unsigned short* base = qkv + (size_t)b * 98 * 768 + h * 32;  // q; +256 k; +512 v

    // ---- stage Q,K (swizzled), V transposed; zero pads ----
    if (tid < 392) {
        const int row = tid >> 2, k8 = tid & 3;
        const unsigned short* rp = base + (size_t)row * 768 + k8 * 8;
        *(int4*)&Qs[sw32(row, k8)] = *(const int4*)(rp);
        *(int4*)&Ks[sw32(row, k8)] = *(const int4*)(rp + 256);
        union { int4 v; unsigned short u[8]; } t;
        t.v = *(const int4*)(rp + 512);   // V[row][8d]
        #pragma unroll
        for (int jj = 0; jj < 8; ++jj) {
            const int d = k8 * 8 + jj;
            Vt[sw128(d, row >> 3) + (row & 7)] = t.u[jj];
        }
    } else {
        const int t2 = tid - 392;                        // 56 threads: zero Q/K pad rows 98..111
        const int row = 98 + (t2 >> 2), k8 = t2 & 3;
        const int4 z = {0, 0, 0, 0};
        *(int4*)&Qs[sw32(row, k8)] = z;
        *(int4*)&Ks[sw32(row, k8)] = z;
    }
    for (int e = tid; e < 32 * 30; e += 448) {           // zero Vt cols 98..127
        const int d = e / 30, n = 98 + e - (e / 30) * 30;
        Vt[sw128(d, n >> 3) + (n & 7)] = 0;
    }
    __syncthreads();

    // ---- S = Q@K^T for row-tile rt = wid ----
    const int rt = wid;
    const bf8v qf = *(const bf8v*)&Qs[sw32(rt * 16 + l16, lg)];
    f32x4 sa[7];
    const f32x4 zero = {0.f, 0.f, 0.f, 0.f};
    #pragma unroll
    for (int ct = 0; ct < 7; ++ct) {
        const bf8v kf = *(const bf8v*)&Ks[sw32(ct * 16 + l16, lg)];
        sa[ct] = __builtin_amdgcn_mfma_f32_16x16x32_bf16(qf, kf, zero, 0, 0, 0);
    }

    // ---- + bm[112][112] (pads baked in: col>=98 = -1e30, pad rows = 0) ----
    const float* bmp = bm + (size_t)(w * 8 + h) * 12544;
    #pragma unroll
    for (int ct = 0; ct < 7; ++ct) {
        const int col = ct * 16 + l16;
        #pragma unroll
        for (int r = 0; r < 4; ++r) {
            const int row = rt * 16 + lg * 4 + r;
            sa[ct][r] += bmp[row * 112 + col];
        }
    }

    // Q/K frags consumed -> safe to overwrite their LDS with Ps after this barrier
    __syncthreads();

    // ---- softmax per row (rows live in 16-lane groups), write P bf16 to Ps ----
    #pragma unroll
    for (int r = 0; r < 4; ++r) {
        float mx = sa[0][r];
        #pragma unroll
        for (int ct = 1; ct < 7; ++ct) mx = fmaxf(mx, sa[ct][r]);
        #pragma unroll
        for (int off = 1; off < 16; off <<= 1) mx = fmaxf(mx, __shfl_xor(mx, off));
        float sum = 0.f;
        #pragma unroll
        for (int ct = 0; ct < 7; ++ct) { const float e = __expf(sa[ct][r] - mx); sa[ct][r] = e; sum += e; }
        #pragma unroll
        for (int off = 1; off < 16; off <<= 1) sum += __shfl_xor(sum, off);
        const float inv = 1.0f / sum;
        const int row = rt * 16 + lg * 4 + r;
        #pragma unroll
        for (int ct = 0; ct < 7; ++ct) {
            const int col = ct * 16 + l16;
            Ps[sw128(row, col >> 3) + (col & 7)] = f2bf(sa[ct][r] * inv);
        }
    }
    // zero P pad cols 112..127 for this wave's rows (PV K-dim padding)
    #pragma unroll
    for (int e0 = 0; e0 < 4; ++e0) {
        const int e = e0 * 64 + lane;
        const int row = rt * 16 + (e >> 4), col = 112 + (e & 15);
        Ps[sw128(row, col >> 3) + (col & 7)] = 0;
    }
    // P is wave-local (each wave reads only its own rows) -> no barrier needed.

    // ---- O = P @ V ----
    f32x4 oacc[2] = {};
    #pragma unroll
    for (int ks = 0; ks < 4; ++ks) {
        const bf8v pf = *(const bf8v*)&Ps[sw128(rt * 16 + l16, ks * 4 + lg)];
        #pragma unroll
        for (int dt = 0; dt < 2; ++dt) {
            const bf8v vf = *(const bf8v*)&Vt[sw128(dt * 16 + l16, ks * 4 + lg)];
            oacc[dt] = __builtin_amdgcn_mfma_f32_16x16x32_bf16(pf, vf, oacc[dt], 0, 0, 0);
        }
    }

    // ---- store att[b][row][h*32 + d] bf16 ----
    #pragma unroll
    for (int r = 0; r < 4; ++r) {
        const int row = rt * 16 + lg * 4 + r;
        if (row < 98) {
            #pragma unroll
            for (int dt = 0; dt < 2; ++dt)
                att[((size_t)b * 98 + row) * 256 + h * 32 + dt * 16 + l16] = f2bf(oacc[dt][r]);
        }
    }
}

// ---------- Kernel 3: out = att @ proj_w + proj_b (bf16 MFMA, fp32 out) ----------
__global__ __launch_bounds__(256) void proj_gemm_kernel(
    const unsigned short* __restrict__ A, const unsigned short* __restrict__ B,
    const float* __restrict__ pb, float* __restrict__ out)
{
    __shared__ unsigned short As[128 * 32];
    __shared__ unsigned short Bs[128 * 32];
    const int tid = threadIdx.x;
    const int lane = tid & 63, wid = tid >> 6;
    const int l16 = lane & 15, lg = lane >> 4;
    const int wr = wid >> 1, wc = wid & 1;
    const int nb = (blockIdx.x & 7) * 98 + (blockIdx.x >> 3);
    const int bm0 = (nb >> 1) * 128, bn0 = (nb & 1) * 128;

    f32x4 acc[4][4] = {};
    const int crow = tid >> 2, ck8 = tid & 3;

    for (int k0 = 0; k0 < 256; k0 += 32) {
        __syncthreads();
        *(int4*)&As[sw32(crow,      ck8)] = *(const int4*)(A + (size_t)(bm0 + crow     ) * 256 + k0 + ck8 * 8);
        *(int4*)&As[sw32(crow + 64, ck8)] = *(const int4*)(A + (size_t)(bm0 + crow + 64) * 256 + k0 + ck8 * 8);
        *(int4*)&Bs[sw32(crow,      ck8)] = *(const int4*)(B + (size_t)(bn0 + crow     ) * 256 + k0 + ck8 * 8);
        *(int4*)&Bs[sw32(crow + 64, ck8)] = *(const int4*)(B + (size_t)(bn0 + crow + 64) * 256 + k0 + ck8 * 8);
        __syncthreads();
        bf8v af[4], bfr[4];
        #pragma unroll
        for (int mt = 0; mt < 4; ++mt) af[mt]  = *(const bf8v*)&As[sw32(wr*64 + mt*16 + l16, lg)];
        #pragma unroll
        for (int nt = 0; nt < 4; ++nt) bfr[nt] = *(const bf8v*)&Bs[sw32(wc*64 + nt*16 + l16, lg)];
        #pragma unroll
        for (int mt = 0; mt < 4; ++mt)
            #pragma unroll
            for (int nt = 0; nt < 4; ++nt)
                acc[mt][nt] = __builtin_amdgcn_mfma_f32_16x16x32_bf16(af[mt], bfr[nt], acc[mt][nt], 0, 0, 0);
    }

    #pragma unroll
    for (int mt = 0; mt < 4; ++mt)
        #pragma unroll
        for (int r = 0; r < 4; ++r) {
            const int row = bm0 + wr*64 + mt*16 + lg*4 + r;
            #pragma unroll
            for (int nt = 0; nt < 4; ++nt) {
                const int col = bn0 + wc*64 + nt*16 + l16;
                out[(size_t)row * 256 + col] = acc[mt][nt][r] + pb[col];
            }
        }
}

extern "C" void kernel_launch(void* const* d_in, const int* in_sizes, int n_in,
                              void* d_out, int out_size, void* d_ws, size_t ws_size,
                              hipStream_t stream) {
    const float* x          = (const float*)d_in[0];
    const float* qkv_w      = (const float*)d_in[1];
    const float* qkv_b      = (const float*)d_in[2];
    const float* bias_table = (const float*)d_in[3];
    const float* proj_w     = (const float*)d_in[4];
    const float* proj_b     = (const float*)d_in[5];
    const float* mask       = (const float*)d_in[6];
    const int*   rpi        = (const int*)d_in[7];
    float* out = (float*)d_out;

    // ws layout (ushorts unless noted): wtq | wtp | qkv | att | bm(f32)
    const size_t SEG = (size_t)50176 * 256;  // 12,845,056
    unsigned short* wtq  = (unsigned short*)d_ws;   // 768*256
    unsigned short* wtp  = wtq + 768 * 256;         // 256*256
    unsigned short* qkvb = wtp + 256 * 256;         // 3*SEG, packed [M][768]
    unsigned short* attb = qkvb + 3 * SEG;          // SEG
    float* bm = (float*)(attb + SEG);               // 512*12544 floats

    tcvt_w_kernel<<<1024, 256, 0, stream>>>(qkv_w, proj_w, wtq, wtp);
    bm_kernel<<<512, 256, 0, stream>>>(bias_table, rpi, mask, bm);

    qkv_gemm_kernel<<<2352, 256, 0, stream>>>(x, wtq, qkv_b, qkvb);
    attn_kernel<<<4096, 448, 0, stream>>>(qkvb, bm, attb);
    proj_gemm_kernel<<<784, 256, 0, stream>>>(attb, wtp, proj_b, out);
}